// Round 15
// baseline (26.129 us; speedup 1.0000x reference)
//
#include <hip/hip_runtime.h>

#define Nn 8
#define Cc 4
#define Hh 256
#define Ww 256

typedef unsigned int u32;
typedef unsigned short u16;
typedef u16 u16x4 __attribute__((ext_vector_type(4)));
typedef unsigned long long u64;

// Workspace layout (bytes):
//   acc : i64 (as u64) quantized-sum accumulator   @ 0
//   cnt : u32 arrival counter                      @ 8
// Both zeroed each call by a 16-byte hipMemsetAsync node.

// ---------------------------------------------------------------------------
// Single merged kernel: block = 1024 thr (16 waves), 16i x 64j tile,
// 1 px/thread. R15 changes vs R14:
//  * 3-chunk tgt loads + 3 ballots/row (window spans chunks jt-1..jt+1 only);
//    U-word mapping identical to R14's V=[0,W0..W7,0] (verified per jt).
//  * deterministic integer-atomic tail replaces partials[] + finalize kernel:
//    q = llrint(v * 2^20) (i64 adds commute -> bitwise deterministic; total
//    quant error <= 512 * 2^-21 raw -> ~1e-10 in output). acc-add completion
//    forced (asm consume of returned old) BEFORE cnt-add, so the block that
//    sees old-cnt == 511 knows every acc-add has landed; it reads the final
//    sum (atomicAdd(acc,0)) and writes out[0]. No __threadfence (R6 lesson).
// Exactness chain unchanged from R14 (clamp-10 + >81 => exact brute-force).
// ---------------------------------------------------------------------------
__global__ __launch_bounds__(1024) void merged_kernel(
    const int* __restrict__ tgt, const float* __restrict__ in,
    u64* __restrict__ acc, u32* __restrict__ cnt, float* __restrict__ out) {
  __shared__ u16x4 s2[32][64];    // sat g^2, row r <-> k = i0-8+r = 16 KB
  __shared__ float s_w[16];
  const int bid = blockIdx.x;     // n*64 + it*4 + jt  (8*16*4 = 512)
  const int n = bid >> 6;
  const int it = (bid >> 2) & 15;
  const int jt = bid & 3;
  const int i0 = it * 16, j0 = jt * 64;
  const int tid = threadIdx.x;
  const int lane = tid & 63;
  const int w = tid >> 6;         // wave 0..15; pixel row i = i0 + w
  const int j = j0 + lane;
  const int i = i0 + w;

  // ---- logit loads up front (consumed only in the loss phase) ----
  const long cs = (long)Hh * Ww;
  const float* lp = in + ((long)(n * Cc) * Hh + i) * Ww + j;
  const float x0 = lp[0];
  const float x1 = lp[cs];
  const float x2 = lp[2 * cs];
  const float x3 = lp[3 * cs];

  // ---- tgt loads: 3 chunks (jt-1, jt, jt+1; clamped addr, masked later) ----
  const int k0r = i0 - 8 + 2 * w;
  const int cm1 = (jt == 0) ? 0 : (jt - 1);
  const int cp1 = (jt == 3) ? 3 : (jt + 1);
  int t_[2][3];
#pragma unroll
  for (int rr = 0; rr < 2; ++rr) {
    const int kc = min(max(k0r + rr, 0), Hh - 1);
    const int rowOff = (n * Hh + kc) * Ww + lane;
    t_[rr][0] = tgt[rowOff + cm1 * 64];
    t_[rr][1] = tgt[rowOff + jt * 64];
    t_[rr][2] = tgt[rowOff + cp1 * 64];
  }

  // ---- per-thread window constants (hoisted) ----
  const int lane16 = lane + 16;
  const bool c0 = (lane16 < 32);
  const bool c1 = (lane16 >= 32) && (lane16 < 64);
  const u32 shift = (u32)(lane16 & 31);
  const u16 SENT = 0xFE00;        // 65024; +dd(<=64) < 65536, no wrap

  // ---- wave-local mask build + 32-bit funnel -> clamped g^2 -> s2 ----
#pragma unroll
  for (int rr = 0; rr < 2; ++rr) {
    const int r = 2 * w + rr;
    const int k = k0r + rr;
    u16x4 sq = {SENT, SENT, SENT, SENT};
    if (k >= 0 && k < Hh) {             // wave-uniform
      u16 dv[4];
#pragma unroll
      for (int c = 0; c < Cc; ++c) {
        const u64 Bm1 = __ballot(t_[rr][0] == c);  // chunk jt-1
        const u64 B0  = __ballot(t_[rr][1] == c);  // chunk jt
        const u64 Bp1 = __ballot(t_[rr][2] == c);  // chunk jt+1
        // U_m = V[2*jt+m], V=[0,W0..W7,0]  (jt uniform -> scalar selects)
        const u32 U0 = (jt == 0) ? 0u : (u32)(Bm1 >> 32);
        const u32 U1 = (u32)B0;
        const u32 U2 = (u32)(B0 >> 32);
        const u32 U3 = (jt == 3) ? 0u : (u32)Bp1;
        const u32 lo = c0 ? U0 : (c1 ? U1 : U2);
        const u32 hi = c0 ? U1 : (c1 ? U2 : U3);
        const u32 win = __builtin_amdgcn_alignbit(hi, lo, shift);
        const u32 ml = win & 0x1FFFFu;  // cols [j-16, j] (bit 16 = col j)
        const u32 mr = win >> 16;       // cols [j, j+15]
        const int dl = __builtin_clz(ml | 1u) - 15;   // ml==0 -> 16 (safe)
        const int dr = __builtin_ctz(mr | 0x10000u);  // mr==0 -> 16 (safe)
        const int dd = min(min(dl, dr), 10);
        dv[c] = (u16)(dd * dd);
      }
      sq.x = dv[0]; sq.y = dv[1]; sq.z = dv[2]; sq.w = dv[3];
    }
    s2[r][lane] = sq;
  }
  __syncthreads();                // the ONLY barrier before the reduction

  // ---- 17-tap column window, symmetric pairs: rows w .. w+16 ----
  u16x4 acc4 = s2[w + 8][lane];   // o = 0: the pixel's own row
#pragma unroll
  for (int o = 1; o <= 8; ++o) {
    const u16x4 pr =
        __builtin_elementwise_min(s2[w + 8 - o][lane], s2[w + 8 + o][lane]);
    const u16 dd = (u16)(o * o);
    const u16x4 ddv = {dd, dd, dd, dd};
    acc4 = __builtin_elementwise_min(acc4, pr + ddv);
  }
  int d0 = acc4.x, d1 = acc4.y, d2 = acc4.z, d3 = acc4.w;

  // ---- exactness check; rare EXACT brute-force fallback ----
  if (max(max(d0, d1), max(d2, d3)) > 81) {   // P ~ 1e-26, exact if taken
    d0 = 0x7fffffff; d1 = 0x7fffffff; d2 = 0x7fffffff; d3 = 0x7fffffff;
    const int* tp = tgt + n * (Hh * Ww);
    for (int p = 0; p < Hh * Ww; ++p) {
      const int t = tp[p];
      const int dy = i - (p >> 8);
      const int dx = j - (p & 255);
      const int dd2 = dy * dy + dx * dx;
      d0 = (t == 0) ? min(d0, dd2) : d0;
      d1 = (t == 1) ? min(d1, dd2) : d1;
      d2 = (t == 2) ? min(d2, dd2) : d2;
      d3 = (t == 3) ? min(d3, dd2) : d3;
    }
  }

  // ---- softmax + loss (HW-approx sqrt/rcp, ~1 ulp) ----
  const float f0 = (float)d0, f1 = (float)d1;  // exact: < 2^24
  const float f2 = (float)d2, f3 = (float)d3;
  const float mx = fmaxf(fmaxf(x0, x1), fmaxf(x2, x3));
  const float e0 = __expf(x0 - mx), e1 = __expf(x1 - mx);
  const float e2 = __expf(x2 - mx), e3 = __expf(x3 - mx);
  const float rs = __builtin_amdgcn_rcpf(e0 + e1 + e2 + e3);
  const float p0 = e0 * rs, p1 = e1 * rs, p2 = e2 * rs, p3 = e3 * rs;
  // own-class d is exactly 0; exclude it for dbar
  const int q0 = (d0 == 0) ? 0x7fffffff : d0;
  const int q1 = (d1 == 0) ? 0x7fffffff : d1;
  const int q2 = (d2 == 0) ? 0x7fffffff : d2;
  const int q3 = (d3 == 0) ? 0x7fffffff : d3;
  const float dbar = (float)min(min(q0, q1), min(q2, q3));
  const float pt = (d0 == 0) ? p0 : (d1 == 0) ? p1 : (d2 == 0) ? p2 : p3;
  float contrib = pt * __builtin_amdgcn_sqrtf(dbar) -
                  (p0 * __builtin_amdgcn_sqrtf(f0) +
                   p1 * __builtin_amdgcn_sqrtf(f1) +
                   p2 * __builtin_amdgcn_sqrtf(f2) +
                   p3 * __builtin_amdgcn_sqrtf(f3));

  // ---- block reduction (deterministic fixed order) ----
#pragma unroll
  for (int off = 32; off > 0; off >>= 1) contrib += __shfl_down(contrib, off);
  if (lane == 0) s_w[w] = contrib;
  __syncthreads();
  if (tid == 0) {
    float v = 0.0f;
#pragma unroll
    for (int q = 0; q < 16; ++q) v += s_w[q];
    // deterministic integer-atomic tail
    const long long qi = (long long)llrintf(v * 1048576.0f);  // 2^20
    const u64 oldacc = atomicAdd(acc, (u64)qi);
    asm volatile("" ::"v"(oldacc));     // force acc-add completion first
    const u32 oldc = atomicAdd(cnt, 1u);
    if (oldc == 511u) {                 // last block: all acc-adds landed
      const u64 tot = atomicAdd(acc, 0ull);
      const double sum = (double)(long long)tot * (1.0 / 1048576.0);
      out[0] = (float)(sum / (double)(Cc * Nn) / (65536.0 + 1e-6));
    }
  }
}

extern "C" void kernel_launch(void* const* d_in, const int* in_sizes, int n_in,
                              void* d_out, int out_size, void* d_ws, size_t ws_size,
                              hipStream_t stream) {
  const float* input = (const float*)d_in[0];   // [8,4,256,256] fp32 logits
  const int* target = (const int*)d_in[1];      // [8,256,256] int32
  float* out = (float*)d_out;                   // scalar fp32
  u64* acc = (u64*)d_ws;
  u32* cnt = (u32*)((char*)d_ws + 8);

  hipMemsetAsync(d_ws, 0, 16, stream);          // zero acc+cnt (graph-safe)
  merged_kernel<<<dim3(512), dim3(1024), 0, stream>>>(target, input, acc, cnt,
                                                      out);
}

// Round 16
// 13.025 us; speedup vs baseline: 2.0060x; 2.0060x over previous
//
#include <hip/hip_runtime.h>

#define Nn 8
#define Cc 4
#define Hh 256
#define Ww 256

typedef unsigned int u32;
typedef unsigned short u16;
typedef u16 u16x4 __attribute__((ext_vector_type(4)));
typedef unsigned long long u64;

// Workspace layout (bytes): partials only
#define OFF_PART 0

// ---------------------------------------------------------------------------
// Merged kernel: block = 1024 thr (16 waves), 16i x 64j tile, 1 px/thread.
// R16 = R14 structure (partials + finalize kernel; plain stores — the R15
// integer-atomic + memset tail cost +12 us and is reverted) + R15's proven
// 3-chunk/3-ballot mask build (window spans chunks jt-1..jt+1 only).
// Exactness chain unchanged: clamp-10 only perturbs g^2 >= 100 > 81; window
// min <= 81 provably exact; else EXACT brute-force fallback (P ~ 1e-26).
// ---------------------------------------------------------------------------
__global__ __launch_bounds__(1024) void merged_kernel(
    const int* __restrict__ tgt, const float* __restrict__ in,
    float* __restrict__ partials) {
  __shared__ u16x4 s2[32][64];    // sat g^2, row r <-> k = i0-8+r = 16 KB
  __shared__ float s_w[16];
  const int bid = blockIdx.x;     // n*64 + it*4 + jt  (8*16*4 = 512)
  const int n = bid >> 6;
  const int it = (bid >> 2) & 15;
  const int jt = bid & 3;
  const int i0 = it * 16, j0 = jt * 64;
  const int tid = threadIdx.x;
  const int lane = tid & 63;
  const int w = tid >> 6;         // wave 0..15; pixel row i = i0 + w
  const int j = j0 + lane;
  const int i = i0 + w;

  // ---- logit loads up front (consumed only in the loss phase) ----
  const long cs = (long)Hh * Ww;
  const float* lp = in + ((long)(n * Cc) * Hh + i) * Ww + j;
  const float x0 = lp[0];
  const float x1 = lp[cs];
  const float x2 = lp[2 * cs];
  const float x3 = lp[3 * cs];

  // ---- tgt loads: 3 chunks (jt-1, jt, jt+1; clamped addr) ----
  const int k0r = i0 - 8 + 2 * w;
  const int cm1 = (jt == 0) ? 0 : (jt - 1);
  const int cp1 = (jt == 3) ? 3 : (jt + 1);
  int t_[2][3];
#pragma unroll
  for (int rr = 0; rr < 2; ++rr) {
    const int kc = min(max(k0r + rr, 0), Hh - 1);
    const int rowOff = (n * Hh + kc) * Ww + lane;
    t_[rr][0] = tgt[rowOff + cm1 * 64];
    t_[rr][1] = tgt[rowOff + jt * 64];
    t_[rr][2] = tgt[rowOff + cp1 * 64];
  }

  // ---- per-thread window constants (hoisted) ----
  const int lane16 = lane + 16;
  const bool c0 = (lane16 < 32);
  const bool c1 = (lane16 >= 32) && (lane16 < 64);
  const u32 shift = (u32)(lane16 & 31);
  const u16 SENT = 0xFE00;        // 65024; +dd(<=64) < 65536, no wrap

  // ---- wave-local mask build + 32-bit funnel -> clamped g^2 -> s2 ----
#pragma unroll
  for (int rr = 0; rr < 2; ++rr) {
    const int r = 2 * w + rr;
    const int k = k0r + rr;
    u16x4 sq = {SENT, SENT, SENT, SENT};
    if (k >= 0 && k < Hh) {             // wave-uniform
      u16 dv[4];
#pragma unroll
      for (int c = 0; c < Cc; ++c) {
        const u64 Bm1 = __ballot(t_[rr][0] == c);  // chunk jt-1
        const u64 B0  = __ballot(t_[rr][1] == c);  // chunk jt
        const u64 Bp1 = __ballot(t_[rr][2] == c);  // chunk jt+1
        // U_m = V[2*jt+m], V=[0,W0..W7,0]  (jt uniform -> scalar selects)
        const u32 U0 = (jt == 0) ? 0u : (u32)(Bm1 >> 32);
        const u32 U1 = (u32)B0;
        const u32 U2 = (u32)(B0 >> 32);
        const u32 U3 = (jt == 3) ? 0u : (u32)Bp1;
        const u32 lo = c0 ? U0 : (c1 ? U1 : U2);
        const u32 hi = c0 ? U1 : (c1 ? U2 : U3);
        const u32 win = __builtin_amdgcn_alignbit(hi, lo, shift);
        const u32 ml = win & 0x1FFFFu;  // cols [j-16, j] (bit 16 = col j)
        const u32 mr = win >> 16;       // cols [j, j+15]
        const int dl = __builtin_clz(ml | 1u) - 15;   // ml==0 -> 16 (safe)
        const int dr = __builtin_ctz(mr | 0x10000u);  // mr==0 -> 16 (safe)
        const int dd = min(min(dl, dr), 10);
        dv[c] = (u16)(dd * dd);
      }
      sq.x = dv[0]; sq.y = dv[1]; sq.z = dv[2]; sq.w = dv[3];
    }
    s2[r][lane] = sq;
  }
  __syncthreads();                // the ONLY barrier before the reduction

  // ---- 17-tap column window, symmetric pairs: rows w .. w+16 ----
  u16x4 acc4 = s2[w + 8][lane];   // o = 0: the pixel's own row
#pragma unroll
  for (int o = 1; o <= 8; ++o) {
    const u16x4 pr =
        __builtin_elementwise_min(s2[w + 8 - o][lane], s2[w + 8 + o][lane]);
    const u16 dd = (u16)(o * o);
    const u16x4 ddv = {dd, dd, dd, dd};
    acc4 = __builtin_elementwise_min(acc4, pr + ddv);
  }
  int d0 = acc4.x, d1 = acc4.y, d2 = acc4.z, d3 = acc4.w;

  // ---- exactness check; rare EXACT brute-force fallback ----
  if (max(max(d0, d1), max(d2, d3)) > 81) {   // P ~ 1e-26, exact if taken
    d0 = 0x7fffffff; d1 = 0x7fffffff; d2 = 0x7fffffff; d3 = 0x7fffffff;
    const int* tp = tgt + n * (Hh * Ww);
    for (int p = 0; p < Hh * Ww; ++p) {
      const int t = tp[p];
      const int dy = i - (p >> 8);
      const int dx = j - (p & 255);
      const int dd2 = dy * dy + dx * dx;
      d0 = (t == 0) ? min(d0, dd2) : d0;
      d1 = (t == 1) ? min(d1, dd2) : d1;
      d2 = (t == 2) ? min(d2, dd2) : d2;
      d3 = (t == 3) ? min(d3, dd2) : d3;
    }
  }

  // ---- softmax + loss (HW-approx sqrt/rcp, ~1 ulp) ----
  const float f0 = (float)d0, f1 = (float)d1;  // exact: < 2^24
  const float f2 = (float)d2, f3 = (float)d3;
  const float mx = fmaxf(fmaxf(x0, x1), fmaxf(x2, x3));
  const float e0 = __expf(x0 - mx), e1 = __expf(x1 - mx);
  const float e2 = __expf(x2 - mx), e3 = __expf(x3 - mx);
  const float rs = __builtin_amdgcn_rcpf(e0 + e1 + e2 + e3);
  const float p0 = e0 * rs, p1 = e1 * rs, p2 = e2 * rs, p3 = e3 * rs;
  // own-class d is exactly 0; exclude it for dbar
  const int q0 = (d0 == 0) ? 0x7fffffff : d0;
  const int q1 = (d1 == 0) ? 0x7fffffff : d1;
  const int q2 = (d2 == 0) ? 0x7fffffff : d2;
  const int q3 = (d3 == 0) ? 0x7fffffff : d3;
  const float dbar = (float)min(min(q0, q1), min(q2, q3));
  const float pt = (d0 == 0) ? p0 : (d1 == 0) ? p1 : (d2 == 0) ? p2 : p3;
  float contrib = pt * __builtin_amdgcn_sqrtf(dbar) -
                  (p0 * __builtin_amdgcn_sqrtf(f0) +
                   p1 * __builtin_amdgcn_sqrtf(f1) +
                   p2 * __builtin_amdgcn_sqrtf(f2) +
                   p3 * __builtin_amdgcn_sqrtf(f3));

  // ---- block reduction (deterministic fixed order) ----
#pragma unroll
  for (int off = 32; off > 0; off >>= 1) contrib += __shfl_down(contrib, off);
  if (lane == 0) s_w[w] = contrib;
  __syncthreads();
  if (tid == 0) {
    float v = 0.0f;
#pragma unroll
    for (int q = 0; q < 16; ++q) v += s_w[q];
    partials[bid] = v;            // plain store (no fence/ticket/atomics)
  }
}

// ---------------------------------------------------------------------------
// Finalize: deterministic reduction of 512 partials + scaling
// ---------------------------------------------------------------------------
__global__ __launch_bounds__(256) void finalize_kernel(
    const float* __restrict__ partials, float* __restrict__ out) {
  __shared__ float s_red[256];
  const int tid = threadIdx.x;
  const float v0 = partials[tid];
  const float v1 = partials[tid + 256];
  s_red[tid] = v0 + v1;
  __syncthreads();
  for (int st = 128; st > 0; st >>= 1) {
    if (tid < st) s_red[tid] += s_red[tid + st];
    __syncthreads();
  }
  if (tid == 0)
    out[0] = s_red[0] / (float)(Cc * Nn) / (65536.0f + 1e-6f);
}

extern "C" void kernel_launch(void* const* d_in, const int* in_sizes, int n_in,
                              void* d_out, int out_size, void* d_ws, size_t ws_size,
                              hipStream_t stream) {
  const float* input = (const float*)d_in[0];   // [8,4,256,256] fp32 logits
  const int* target = (const int*)d_in[1];      // [8,256,256] int32
  float* out = (float*)d_out;                   // scalar fp32
  float* partials = (float*)((char*)d_ws + OFF_PART);

  merged_kernel<<<dim3(512), dim3(1024), 0, stream>>>(target, input, partials);
  finalize_kernel<<<dim3(1), dim3(256), 0, stream>>>(partials, out);
}

// Round 17
// 12.509 us; speedup vs baseline: 2.0887x; 1.0412x over previous
//
#include <hip/hip_runtime.h>

#define Nn 8
#define Cc 4
#define Hh 256
#define Ww 256

typedef unsigned int u32;
typedef unsigned short u16;
typedef u16 u16x4 __attribute__((ext_vector_type(4)));
typedef unsigned long long u64;

// Workspace layout (bytes): partials only
#define OFF_PART 0

// ---------------------------------------------------------------------------
// Merged kernel: block = 1024 thr (16 waves), 32i x 64j tile, 2 px/thread.
// R17 vs R16 (single variable = tile geometry):
//  * tile 16i -> 32i: halo duplication 32/16 = 2.0x -> 48/32 = 1.5x on the
//    ballot+funnel phase (x0.75 total); grid 512 -> 256 (half dispatch ramp).
//  * thread (w, lane) computes g^2 rows {w, w+16, w+32} and pixels
//    {i0+w, i0+w+16}; all row indices wave-uniform.
//  * trade-off probed: occupancy 32 -> 16 waves/CU (1 block/CU, 24 KB LDS).
// Funnel math, clamp-10 exactness chain, fallback, softmax, reduction tail:
// identical to R16.
// ---------------------------------------------------------------------------
__global__ __launch_bounds__(1024) void merged_kernel(
    const int* __restrict__ tgt, const float* __restrict__ in,
    float* __restrict__ partials) {
  __shared__ u16x4 s2[48][64];    // sat g^2, row r <-> k = i0-8+r = 24 KB
  __shared__ float s_w[16];
  const int bid = blockIdx.x;     // n*32 + it*4 + jt  (8*8*4 = 256)
  const int n = bid >> 5;
  const int it = (bid >> 2) & 7;
  const int jt = bid & 3;
  const int i0 = it * 32, j0 = jt * 64;
  const int tid = threadIdx.x;
  const int lane = tid & 63;
  const int w = tid >> 6;         // wave 0..15
  const int j = j0 + lane;

  // ---- logit loads up front: 2 pixels x 4 classes ----
  const long cs = (long)Hh * Ww;
  float x[2][4];
#pragma unroll
  for (int px = 0; px < 2; ++px) {
    const int i = i0 + w + px * 16;
    const float* lp = in + ((long)(n * Cc) * Hh + i) * Ww + j;
#pragma unroll
    for (int c = 0; c < 4; ++c) x[px][c] = lp[c * cs];
  }

  // ---- tgt loads: 3 rows (r = w + 16q) x 3 chunks (clamped addr) ----
  const int cm1 = (jt == 0) ? 0 : (jt - 1);
  const int cp1 = (jt == 3) ? 3 : (jt + 1);
  int t_[3][3];
#pragma unroll
  for (int q = 0; q < 3; ++q) {
    const int k = i0 - 8 + w + 16 * q;
    const int kc = min(max(k, 0), Hh - 1);
    const int rowOff = (n * Hh + kc) * Ww + lane;
    t_[q][0] = tgt[rowOff + cm1 * 64];
    t_[q][1] = tgt[rowOff + jt * 64];
    t_[q][2] = tgt[rowOff + cp1 * 64];
  }

  // ---- per-thread window constants (hoisted) ----
  const int lane16 = lane + 16;
  const bool c0 = (lane16 < 32);
  const bool c1 = (lane16 >= 32) && (lane16 < 64);
  const u32 shift = (u32)(lane16 & 31);
  const u16 SENT = 0xFE00;        // 65024; +dd(<=64) < 65536, no wrap

  // ---- wave-local mask build + 32-bit funnel -> clamped g^2 -> s2 ----
#pragma unroll
  for (int q = 0; q < 3; ++q) {
    const int r = w + 16 * q;
    const int k = i0 - 8 + r;
    u16x4 sq = {SENT, SENT, SENT, SENT};
    if (k >= 0 && k < Hh) {             // wave-uniform
      u16 dv[4];
#pragma unroll
      for (int c = 0; c < Cc; ++c) {
        const u64 Bm1 = __ballot(t_[q][0] == c);  // chunk jt-1
        const u64 B0  = __ballot(t_[q][1] == c);  // chunk jt
        const u64 Bp1 = __ballot(t_[q][2] == c);  // chunk jt+1
        // U_m = V[2*jt+m], V=[0,W0..W7,0]  (jt uniform -> scalar selects)
        const u32 U0 = (jt == 0) ? 0u : (u32)(Bm1 >> 32);
        const u32 U1 = (u32)B0;
        const u32 U2 = (u32)(B0 >> 32);
        const u32 U3 = (jt == 3) ? 0u : (u32)Bp1;
        const u32 lo = c0 ? U0 : (c1 ? U1 : U2);
        const u32 hi = c0 ? U1 : (c1 ? U2 : U3);
        const u32 win = __builtin_amdgcn_alignbit(hi, lo, shift);
        const u32 ml = win & 0x1FFFFu;  // cols [j-16, j] (bit 16 = col j)
        const u32 mr = win >> 16;       // cols [j, j+15]
        const int dl = __builtin_clz(ml | 1u) - 15;   // ml==0 -> 16 (safe)
        const int dr = __builtin_ctz(mr | 0x10000u);  // mr==0 -> 16 (safe)
        const int dd = min(min(dl, dr), 10);
        dv[c] = (u16)(dd * dd);
      }
      sq.x = dv[0]; sq.y = dv[1]; sq.z = dv[2]; sq.w = dv[3];
    }
    s2[r][lane] = sq;
  }
  __syncthreads();                // the ONLY barrier before the reduction

  // ---- per pixel: 17-tap window, fallback, softmax, loss ----
  float contrib = 0.0f;
#pragma unroll
  for (int px = 0; px < 2; ++px) {
    const int ctr = w + 8 + px * 16;    // window center row in s2
    const int i = i0 + w + px * 16;
    u16x4 acc4 = s2[ctr][lane];         // o = 0
#pragma unroll
    for (int o = 1; o <= 8; ++o) {
      const u16x4 pr =
          __builtin_elementwise_min(s2[ctr - o][lane], s2[ctr + o][lane]);
      const u16 dd = (u16)(o * o);
      const u16x4 ddv = {dd, dd, dd, dd};
      acc4 = __builtin_elementwise_min(acc4, pr + ddv);
    }
    int d0 = acc4.x, d1 = acc4.y, d2 = acc4.z, d3 = acc4.w;

    // exactness check; rare EXACT brute-force fallback (P ~ 1e-26)
    if (max(max(d0, d1), max(d2, d3)) > 81) {
      d0 = 0x7fffffff; d1 = 0x7fffffff; d2 = 0x7fffffff; d3 = 0x7fffffff;
      const int* tp = tgt + n * (Hh * Ww);
      for (int p = 0; p < Hh * Ww; ++p) {
        const int t = tp[p];
        const int dy = i - (p >> 8);
        const int dx = j - (p & 255);
        const int dd2 = dy * dy + dx * dx;
        d0 = (t == 0) ? min(d0, dd2) : d0;
        d1 = (t == 1) ? min(d1, dd2) : d1;
        d2 = (t == 2) ? min(d2, dd2) : d2;
        d3 = (t == 3) ? min(d3, dd2) : d3;
      }
    }

    // softmax + loss (HW-approx sqrt/rcp, ~1 ulp)
    const float f0 = (float)d0, f1 = (float)d1;  // exact: < 2^24
    const float f2 = (float)d2, f3 = (float)d3;
    const float mx = fmaxf(fmaxf(x[px][0], x[px][1]),
                           fmaxf(x[px][2], x[px][3]));
    const float e0 = __expf(x[px][0] - mx), e1 = __expf(x[px][1] - mx);
    const float e2 = __expf(x[px][2] - mx), e3 = __expf(x[px][3] - mx);
    const float rs = __builtin_amdgcn_rcpf(e0 + e1 + e2 + e3);
    const float p0 = e0 * rs, p1 = e1 * rs, p2 = e2 * rs, p3 = e3 * rs;
    // own-class d is exactly 0; exclude it for dbar
    const int q0 = (d0 == 0) ? 0x7fffffff : d0;
    const int q1 = (d1 == 0) ? 0x7fffffff : d1;
    const int q2 = (d2 == 0) ? 0x7fffffff : d2;
    const int q3 = (d3 == 0) ? 0x7fffffff : d3;
    const float dbar = (float)min(min(q0, q1), min(q2, q3));
    const float pt = (d0 == 0) ? p0 : (d1 == 0) ? p1 : (d2 == 0) ? p2 : p3;
    contrib += pt * __builtin_amdgcn_sqrtf(dbar) -
               (p0 * __builtin_amdgcn_sqrtf(f0) +
                p1 * __builtin_amdgcn_sqrtf(f1) +
                p2 * __builtin_amdgcn_sqrtf(f2) +
                p3 * __builtin_amdgcn_sqrtf(f3));
  }

  // ---- block reduction (deterministic fixed order) ----
#pragma unroll
  for (int off = 32; off > 0; off >>= 1) contrib += __shfl_down(contrib, off);
  if (lane == 0) s_w[w] = contrib;
  __syncthreads();
  if (tid == 0) {
    float v = 0.0f;
#pragma unroll
    for (int q = 0; q < 16; ++q) v += s_w[q];
    partials[bid] = v;            // plain store (no fence/ticket/atomics)
  }
}

// ---------------------------------------------------------------------------
// Finalize: deterministic reduction of 256 partials + scaling
// ---------------------------------------------------------------------------
__global__ __launch_bounds__(256) void finalize_kernel(
    const float* __restrict__ partials, float* __restrict__ out) {
  __shared__ float s_red[256];
  const int tid = threadIdx.x;
  s_red[tid] = partials[tid];
  __syncthreads();
  for (int st = 128; st > 0; st >>= 1) {
    if (tid < st) s_red[tid] += s_red[tid + st];
    __syncthreads();
  }
  if (tid == 0)
    out[0] = s_red[0] / (float)(Cc * Nn) / (65536.0f + 1e-6f);
}

extern "C" void kernel_launch(void* const* d_in, const int* in_sizes, int n_in,
                              void* d_out, int out_size, void* d_ws, size_t ws_size,
                              hipStream_t stream) {
  const float* input = (const float*)d_in[0];   // [8,4,256,256] fp32 logits
  const int* target = (const int*)d_in[1];      // [8,256,256] int32
  float* out = (float*)d_out;                   // scalar fp32
  float* partials = (float*)((char*)d_ws + OFF_PART);

  merged_kernel<<<dim3(256), dim3(1024), 0, stream>>>(target, input, partials);
  finalize_kernel<<<dim3(1), dim3(256), 0, stream>>>(partials, out);
}